// Round 9
// baseline (317.415 us; speedup 1.0000x reference)
//
#include <hip/hip_runtime.h>
#include <math.h>

typedef unsigned int uint;
typedef unsigned short ushort_t;
typedef float f32x4 __attribute__((ext_vector_type(4)));

// monotonic float<->uint encoding for atomic min/max
__device__ __forceinline__ uint fenc(float f) {
    uint u = __float_as_uint(f);
    return (u & 0x80000000u) ? ~u : (u | 0x80000000u);
}
__device__ __forceinline__ float fdec(uint u) {
    uint v = (u & 0x80000000u) ? (u & 0x7FFFFFFFu) : ~u;
    return __uint_as_float(v);
}

__device__ __forceinline__ void ntst(float* p, float a, float b, float c, float d) {
    f32x4 t; t.x = a; t.y = b; t.z = c; t.w = d;
    __builtin_nontemporal_store(t, (f32x4*)p);
}
__device__ __forceinline__ void cst(float* p, float a, float b, float c, float d) {
    f32x4 t; t.x = a; t.y = b; t.z = c; t.w = d;
    *(f32x4*)p = t;
}

// ---------------------------------------------------------------------------
// init (1 block): flags + negative-weight scan
__global__ __launch_bounds__(256) void init_kernel(uint* __restrict__ flags,
                                                   const float* __restrict__ A,
                                                   int d)
{
    const int t = threadIdx.x;
    if (t == 0) { flags[0] = 0u; flags[1] = 0xFFFFFFFFu; flags[2] = 0u; }
    __syncthreads();
    for (int k = t; k < d; k += 256)
        if (A[k] < 0.f) atomicOr(&flags[0], 1u);
}

// ---------------------------------------------------------------------------
// global min/max of G = |a_d| * F[i][d]
__global__ __launch_bounds__(256) void minmax_kernel(const float* __restrict__ F,
                                                     const float* __restrict__ A,
                                                     uint* __restrict__ flags,
                                                     int n, int d)
{
    const int total4 = n * d / 4;
    float lmin = 3.4e38f, lmax = -3.4e38f;
    for (int e4 = blockIdx.x * 256 + threadIdx.x; e4 < total4; e4 += gridDim.x * 256) {
        int e = e4 * 4;
        int dk = e % d;
        float4 f = *(const float4*)(F + e);
        float4 a = *(const float4*)(A + dk);
        float g0 = fabsf(a.x) * f.x, g1 = fabsf(a.y) * f.y;
        float g2 = fabsf(a.z) * f.z, g3 = fabsf(a.w) * f.w;
        lmin = fminf(lmin, fminf(fminf(g0, g1), fminf(g2, g3)));
        lmax = fmaxf(lmax, fmaxf(fmaxf(g0, g1), fmaxf(g2, g3)));
    }
    #pragma unroll
    for (int m = 1; m < 64; m <<= 1) {
        lmin = fminf(lmin, __shfl_xor(lmin, m));
        lmax = fmaxf(lmax, __shfl_xor(lmax, m));
    }
    if ((threadIdx.x & 63) == 0) {
        atomicMin(&flags[1], fenc(lmin));
        atomicMax(&flags[2], fenc(lmax));
    }
}

// ---------------------------------------------------------------------------
// quantize G = a_d*F (a_d>0 dims; others -> 0) to u8, k-major u32 [d/4][n];
// also zeroes rowsum (block b owns rows b*32..b*32+31).
__global__ __launch_bounds__(256) void quant_kernel(const float* __restrict__ F,
                                                    const float* __restrict__ A,
                                                    const uint* __restrict__ flags,
                                                    uint* __restrict__ Q,
                                                    float* __restrict__ rowsum,
                                                    int n, int d)
{
    const int t = threadIdx.x;
    const int r = blockIdx.x * 32 + (t & 31);
    if (t < 32) rowsum[blockIdx.x * 32 + t] = 0.f;
    const int kqb = t >> 5;
    const int d4 = d >> 2;
    const float gmin = fdec(flags[1]), gmax = fdec(flags[2]);
    const float span = gmax - gmin;
    const float inv = span > 0.f ? 255.f / span : 0.f;
    for (int kq = kqb; kq < d4; kq += 8) {
        float4 f = *(const float4*)(F + (size_t)r * d + kq * 4);
        float4 a = *(const float4*)(A + kq * 4);
        uint q0 = 0, q1 = 0, q2 = 0, q3 = 0;
        if (a.x > 0.f) q0 = (uint)fminf(fmaxf((a.x * f.x - gmin) * inv + 0.5f, 0.f), 255.f);
        if (a.y > 0.f) q1 = (uint)fminf(fmaxf((a.y * f.y - gmin) * inv + 0.5f, 0.f), 255.f);
        if (a.z > 0.f) q2 = (uint)fminf(fmaxf((a.z * f.z - gmin) * inv + 0.5f, 0.f), 255.f);
        if (a.w > 0.f) q3 = (uint)fminf(fmaxf((a.w * f.w - gmin) * inv + 0.5f, 0.f), 255.f);
        Q[(size_t)kq * n + r] = q0 | (q1 << 8) | (q2 << 16) | (q3 << 24);
    }
}

// ---------------------------------------------------------------------------
// shared SAD tile core (r5/r7-proven pipeline)
__device__ __forceinline__ void sad_core(const uint* __restrict__ Q, int n, int chunks,
                                         int i0, int j0, int t,
                                         uint (&acc)[8][8],
                                         uint (&As)[16][128], uint (&Bs)[16][128])
{
    const int tx = t & 15, ty = t >> 4;
    const int kk0 = t >> 5;
    const int col = 4 * (t & 31);

    uint4 sa[2], sb[2];
    #pragma unroll
    for (int j = 0; j < 2; ++j) {
        size_t g = ((size_t)(kk0 + 8 * j)) * n;
        sa[j] = *(const uint4*)(Q + g + i0 + col);
        sb[j] = *(const uint4*)(Q + g + j0 + col);
    }

    for (int c = 0; c < chunks; ++c) {
        ((uint4*)&As[0][0])[t]       = sa[0];
        ((uint4*)&As[0][0])[256 + t] = sa[1];
        ((uint4*)&Bs[0][0])[t]       = sb[0];
        ((uint4*)&Bs[0][0])[256 + t] = sb[1];
        __syncthreads();

        if (c + 1 < chunks) {
            #pragma unroll
            for (int j = 0; j < 2; ++j) {
                size_t g = ((size_t)((c + 1) * 16 + kk0 + 8 * j)) * n;
                sa[j] = *(const uint4*)(Q + g + i0 + col);
                sb[j] = *(const uint4*)(Q + g + j0 + col);
            }
        }

        #pragma unroll
        for (int kk = 0; kk < 16; ++kk) {
            uint ar[8], br[8];
            *(uint4*)&ar[0] = *(const uint4*)&As[kk][4 * ty];
            *(uint4*)&ar[4] = *(const uint4*)&As[kk][64 + 4 * ty];
            *(uint4*)&br[0] = *(const uint4*)&Bs[kk][4 * tx];
            *(uint4*)&br[4] = *(const uint4*)&Bs[kk][64 + 4 * tx];
            #pragma unroll
            for (int m = 0; m < 8; ++m)
                #pragma unroll
                for (int cc = 0; cc < 8; ++cc)
                    acc[m][cc] = __builtin_amdgcn_sad_u8(ar[m], br[cc], acc[m][cc]);
        }
        __syncthreads();
    }
}

// triangular block decode: b -> (bx >= by)
__device__ __forceinline__ void tri_decode(int b, int& bx, int& by) {
    bx = (int)((sqrtf(8.f * (float)b + 1.f) - 1.f) * 0.5f);
    while ((bx + 1) * (bx + 2) / 2 <= b) ++bx;
    while (bx * (bx + 1) / 2 > b) --bx;
    by = b - bx * (bx + 1) / 2;
}

// ---------------------------------------------------------------------------
// Fast path A (big ws): SAD triangle -> u16 SAD stores (EXACT: max 255*256 =
// 65280 < 65536) into each tile's own footprint in the nrm region (first
// 256 B of each 512 B row segment) + rowsum atomics. 4x fewer store bytes
// than r7 -> end-of-kernel burst shrinks 268 -> 67 MB.
__global__ __launch_bounds__(256, 3) void pass1_sad16(const uint* __restrict__ Q,
                                                      const uint* __restrict__ flags,
                                                      ushort_t* s16,   // = (ushort*)nrm
                                                      float* __restrict__ rowsum,
                                                      int n, int d)
{
    if (flags[0] != 0u) return;

    __shared__ uint As[16][128];
    __shared__ uint Bs[16][128];

    int bx, by; tri_decode(blockIdx.x, bx, by);
    const int t = threadIdx.x, tx = t & 15, ty = t >> 4;
    const int i0 = by * 128, j0 = bx * 128;
    const bool diag = (bx == by);

    const float gmin = fdec(flags[1]), gmax = fdec(flags[2]);
    const float nstep = (gmin - gmax) * (1.f / 255.f);   // -step

    uint acc[8][8] = {};
    sad_core(Q, n, (d >> 2) >> 4, i0, j0, t, acc, As, Bs);

    // store u16 SAD into tile footprint (u16 index: (row*n + j0)*2 + c)
    #pragma unroll
    for (int m = 0; m < 8; ++m) {
        const int row = i0 + (m >> 2) * 64 + 4 * ty + (m & 3);
        const size_t rb = ((size_t)row * n + j0) * 2;
        #pragma unroll
        for (int qh = 0; qh < 2; ++qh) {
            uint2 v;
            v.x = (acc[m][qh * 4 + 0] & 0xFFFFu) | (acc[m][qh * 4 + 1] << 16);
            v.y = (acc[m][qh * 4 + 2] & 0xFFFFu) | (acc[m][qh * 4 + 3] << 16);
            *(uint2*)(s16 + rb + qh * 64 + 4 * tx) = v;
        }
    }

    // rowsums (exp in registers only)
    float cs[8] = {0.f, 0.f, 0.f, 0.f, 0.f, 0.f, 0.f, 0.f};
    #pragma unroll
    for (int m = 0; m < 8; ++m) {
        const int row = i0 + (m >> 2) * 64 + 4 * ty + (m & 3);
        float rs = 0.f;
        #pragma unroll
        for (int cc = 0; cc < 8; ++cc) {
            float e = __expf(nstep * (float)acc[m][cc]);
            rs += e; cs[cc] += e;
        }
        rs += __shfl_xor(rs, 1);
        rs += __shfl_xor(rs, 2);
        rs += __shfl_xor(rs, 4);
        rs += __shfl_xor(rs, 8);
        if (tx == 0) atomicAdd(rowsum + row, rs);
    }
    if (!diag) {
        #pragma unroll
        for (int cc = 0; cc < 8; ++cc) {
            float s = cs[cc];
            s += __shfl_xor(s, 16);
            s += __shfl_xor(s, 32);
            cs[cc] = s;
        }
        if ((t & 48) == 0) {
            #pragma unroll
            for (int qh = 0; qh < 2; ++qh)
                #pragma unroll
                for (int cc = 0; cc < 4; ++cc)
                    atomicAdd(rowsum + j0 + qh * 64 + 4 * tx + cc, cs[qh * 4 + cc]);
        }
    }
}

// ---------------------------------------------------------------------------
// Fast path A, pass 2: per upper tile, read own sad16 -> exp -> write adj
// (direct + mirrored) and nrm (direct + mirrored, rsqrt folded). NT stores.
// s16 aliases nrm (loads complete before stores via barrier; mirror targets
// are lower tiles whose footprints never hold sad16).
__global__ __launch_bounds__(256) void norm_tiled(const ushort_t* s16,
                                                  const uint* __restrict__ flags,
                                                  const float* __restrict__ rowsum,
                                                  float* __restrict__ adj,
                                                  float* nrm, int n)
{
    if (flags[0] != 0u) return;

    int bx, by; tri_decode(blockIdx.x, bx, by);
    const int t = threadIdx.x, tx = t & 15, ty = t >> 4;
    const int i0 = by * 128, j0 = bx * 128;
    const bool diag = (bx == by);

    const float gmin = fdec(flags[1]), gmax = fdec(flags[2]);
    const float nstep = (gmin - gmax) * (1.f / 255.f);

    float e[8][8];
    #pragma unroll
    for (int m = 0; m < 8; ++m) {
        const int row = i0 + (m >> 2) * 64 + 4 * ty + (m & 3);
        const size_t rb = ((size_t)row * n + j0) * 2;
        #pragma unroll
        for (int qh = 0; qh < 2; ++qh) {
            uint2 v = *(const uint2*)(s16 + rb + qh * 64 + 4 * tx);
            e[m][qh * 4 + 0] = __expf(nstep * (float)(v.x & 0xFFFFu));
            e[m][qh * 4 + 1] = __expf(nstep * (float)(v.x >> 16));
            e[m][qh * 4 + 2] = __expf(nstep * (float)(v.y & 0xFFFFu));
            e[m][qh * 4 + 3] = __expf(nstep * (float)(v.y >> 16));
        }
    }

    float dr[8], dc[8];
    #pragma unroll
    for (int m = 0; m < 8; ++m)
        dr[m] = rsqrtf(rowsum[i0 + (m >> 2) * 64 + 4 * ty + (m & 3)]);
    {
        float4 c0 = *(const float4*)(rowsum + j0 + 4 * tx);
        float4 c1 = *(const float4*)(rowsum + j0 + 64 + 4 * tx);
        dc[0] = rsqrtf(c0.x); dc[1] = rsqrtf(c0.y);
        dc[2] = rsqrtf(c0.z); dc[3] = rsqrtf(c0.w);
        dc[4] = rsqrtf(c1.x); dc[5] = rsqrtf(c1.y);
        dc[6] = rsqrtf(c1.z); dc[7] = rsqrtf(c1.w);
    }

    __syncthreads();   // all sad16 loads done before nrm overwrites footprint

    // direct tiles (rows i0..)
    #pragma unroll
    for (int m = 0; m < 8; ++m) {
        const int row = i0 + (m >> 2) * 64 + 4 * ty + (m & 3);
        const float dm = dr[m];
        #pragma unroll
        for (int qh = 0; qh < 2; ++qh) {
            float* ap = adj + (size_t)row * n + j0 + qh * 64 + 4 * tx;
            float* np = nrm + (size_t)row * n + j0 + qh * 64 + 4 * tx;
            ntst(ap, e[m][qh * 4 + 0], e[m][qh * 4 + 1],
                     e[m][qh * 4 + 2], e[m][qh * 4 + 3]);
            ntst(np, e[m][qh * 4 + 0] * dm * dc[qh * 4 + 0],
                     e[m][qh * 4 + 1] * dm * dc[qh * 4 + 1],
                     e[m][qh * 4 + 2] * dm * dc[qh * 4 + 2],
                     e[m][qh * 4 + 3] * dm * dc[qh * 4 + 3]);
        }
    }

    // mirrored tiles (rows j0..), off-diagonal only
    if (!diag) {
        #pragma unroll
        for (int h = 0; h < 2; ++h)
            #pragma unroll
            for (int qh = 0; qh < 2; ++qh)
                #pragma unroll
                for (int cc = 0; cc < 4; ++cc) {
                    const int r = j0 + qh * 64 + 4 * tx + cc;
                    const float dcv = dc[qh * 4 + cc];
                    float* ap = adj + (size_t)r * n + i0 + 64 * h + 4 * ty;
                    float* np = nrm + (size_t)r * n + i0 + 64 * h + 4 * ty;
                    ntst(ap, e[4 * h + 0][qh * 4 + cc], e[4 * h + 1][qh * 4 + cc],
                             e[4 * h + 2][qh * 4 + cc], e[4 * h + 3][qh * 4 + cc]);
                    ntst(np, e[4 * h + 0][qh * 4 + cc] * dr[4 * h + 0] * dcv,
                             e[4 * h + 1][qh * 4 + cc] * dr[4 * h + 1] * dcv,
                             e[4 * h + 2][qh * 4 + cc] * dr[4 * h + 2] * dcv,
                             e[4 * h + 3][qh * 4 + cc] * dr[4 * h + 3] * dcv);
                }
    }
}

// ---------------------------------------------------------------------------
// Fallback fast path B (small ws, r7-proven): SAD triangle -> adjacency
// (direct + mirrored) + rowsums.
__global__ __launch_bounds__(256, 3) void pass1_sadW(const uint* __restrict__ Q,
                                                     const uint* __restrict__ flags,
                                                     float* __restrict__ adj,
                                                     float* __restrict__ rowsum,
                                                     int n, int d)
{
    if (flags[0] != 0u) return;

    __shared__ uint As[16][128];
    __shared__ uint Bs[16][128];

    int bx, by; tri_decode(blockIdx.x, bx, by);
    const int t = threadIdx.x, tx = t & 15, ty = t >> 4;
    const int i0 = by * 128, j0 = bx * 128;
    const bool diag = (bx == by);

    const float gmin = fdec(flags[1]), gmax = fdec(flags[2]);
    const float nstep = (gmin - gmax) * (1.f / 255.f);

    uint acc[8][8] = {};
    sad_core(Q, n, (d >> 2) >> 4, i0, j0, t, acc, As, Bs);

    #pragma unroll
    for (int m = 0; m < 8; ++m)
        #pragma unroll
        for (int cc = 0; cc < 8; ++cc)
            acc[m][cc] = __float_as_uint(__expf(nstep * (float)acc[m][cc]));

    #pragma unroll
    for (int m = 0; m < 8; ++m) {
        const int row = i0 + (m >> 2) * 64 + 4 * ty + (m & 3);
        #pragma unroll
        for (int qh = 0; qh < 2; ++qh)
            cst(adj + (size_t)row * n + j0 + qh * 64 + 4 * tx,
                __uint_as_float(acc[m][qh * 4 + 0]),
                __uint_as_float(acc[m][qh * 4 + 1]),
                __uint_as_float(acc[m][qh * 4 + 2]),
                __uint_as_float(acc[m][qh * 4 + 3]));
    }
    if (!diag) {
        #pragma unroll
        for (int h = 0; h < 2; ++h)
            #pragma unroll
            for (int qh = 0; qh < 2; ++qh)
                #pragma unroll
                for (int cc = 0; cc < 4; ++cc) {
                    const int r = j0 + qh * 64 + 4 * tx + cc;
                    cst(adj + (size_t)r * n + i0 + 64 * h + 4 * ty,
                        __uint_as_float(acc[4 * h + 0][qh * 4 + cc]),
                        __uint_as_float(acc[4 * h + 1][qh * 4 + cc]),
                        __uint_as_float(acc[4 * h + 2][qh * 4 + cc]),
                        __uint_as_float(acc[4 * h + 3][qh * 4 + cc]));
                }
    }

    #pragma unroll
    for (int m = 0; m < 8; ++m) {
        const int row = i0 + (m >> 2) * 64 + 4 * ty + (m & 3);
        float rs = 0.f;
        #pragma unroll
        for (int cc = 0; cc < 8; ++cc) rs += __uint_as_float(acc[m][cc]);
        rs += __shfl_xor(rs, 1);
        rs += __shfl_xor(rs, 2);
        rs += __shfl_xor(rs, 4);
        rs += __shfl_xor(rs, 8);
        if (tx == 0) atomicAdd(rowsum + row, rs);
    }
    if (!diag) {
        float cs[8];
        #pragma unroll
        for (int cc = 0; cc < 8; ++cc) {
            float s = 0.f;
            #pragma unroll
            for (int m = 0; m < 8; ++m) s += __uint_as_float(acc[m][cc]);
            s += __shfl_xor(s, 16);
            s += __shfl_xor(s, 32);
            cs[cc] = s;
        }
        if ((t & 48) == 0) {
            #pragma unroll
            for (int qh = 0; qh < 2; ++qh)
                #pragma unroll
                for (int cc = 0; cc < 4; ++cc)
                    atomicAdd(rowsum + j0 + qh * 64 + 4 * tx + cc, cs[qh * 4 + cc]);
        }
    }
}

// ---------------------------------------------------------------------------
// Slow fp32 fallback (negflag!=0): persistent grid over all square tiles.
__global__ __launch_bounds__(256) void adj_fp32_kernel(
    const float* __restrict__ F, const float* __restrict__ A,
    const uint* __restrict__ flags,
    float* __restrict__ adj, float* __restrict__ rowsum, int n, int d)
{
    if (flags[0] == 0u) return;

    __shared__ __align__(16) float As[32][132];
    __shared__ __align__(16) float Bs[32][132];
    __shared__ float aw[256];

    const int t  = threadIdx.x;
    const int tx = t & 15;
    const int ty = t >> 4;
    const int nb = n / 128;

    for (int k = t; k < d; k += 256) aw[k] = A[k];

    for (int bt = blockIdx.x; bt < nb * nb; bt += gridDim.x) {
        const int i0 = (bt / nb) * 128;
        const int j0 = (bt % nb) * 128;

        float acc[2][2][4][4] = {};
        const int lr = t >> 3;
        const int lk = (t & 7) << 2;

        for (int kc = 0; kc < d; kc += 32) {
            __syncthreads();
            #pragma unroll
            for (int s = 0; s < 4; ++s) {
                int r = lr + 32 * s;
                float4 v = *(const float4*)(F + (size_t)(i0 + r) * d + kc + lk);
                As[lk + 0][r] = v.x; As[lk + 1][r] = v.y;
                As[lk + 2][r] = v.z; As[lk + 3][r] = v.w;
                float4 u = *(const float4*)(F + (size_t)(j0 + r) * d + kc + lk);
                Bs[lk + 0][r] = u.x; Bs[lk + 1][r] = u.y;
                Bs[lk + 2][r] = u.z; Bs[lk + 3][r] = u.w;
            }
            __syncthreads();

            #pragma unroll
            for (int k = 0; k < 32; ++k) {
                float av[2][4], bv[2][4];
                *(float4*)&av[0][0] = *(const float4*)&As[k][4 * ty];
                *(float4*)&av[1][0] = *(const float4*)&As[k][64 + 4 * ty];
                *(float4*)&bv[0][0] = *(const float4*)&Bs[k][4 * tx];
                *(float4*)&bv[1][0] = *(const float4*)&Bs[k][64 + 4 * tx];
                const float w = aw[kc + k];
                #pragma unroll
                for (int p = 0; p < 2; ++p)
                    #pragma unroll
                    for (int m = 0; m < 4; ++m)
                        #pragma unroll
                        for (int q = 0; q < 2; ++q)
                            #pragma unroll
                            for (int c = 0; c < 4; ++c)
                                acc[p][q][m][c] += fabsf(av[p][m] - bv[q][c]) * w;
            }
        }

        #pragma unroll
        for (int p = 0; p < 2; ++p) {
            #pragma unroll
            for (int m = 0; m < 4; ++m) {
                const int row = i0 + p * 64 + ty * 4 + m;
                float rs = 0.f;
                #pragma unroll
                for (int q = 0; q < 2; ++q) {
                    float4 v;
                    v.x = __expf(-fmaxf(acc[p][q][m][0], 0.f));
                    v.y = __expf(-fmaxf(acc[p][q][m][1], 0.f));
                    v.z = __expf(-fmaxf(acc[p][q][m][2], 0.f));
                    v.w = __expf(-fmaxf(acc[p][q][m][3], 0.f));
                    rs += (v.x + v.y) + (v.z + v.w);
                    *(float4*)(adj + (size_t)row * n + j0 + q * 64 + tx * 4) = v;
                }
                rs += __shfl_xor(rs, 1);
                rs += __shfl_xor(rs, 2);
                rs += __shfl_xor(rs, 4);
                rs += __shfl_xor(rs, 8);
                if (tx == 0) atomicAdd(rowsum + row, rs);
            }
        }
        __syncthreads();
    }
}

// ---------------------------------------------------------------------------
// linear norm (rsqrt folded): gate=1 -> only when negflag set (fast-A flow);
// gate=0 -> always (fallback flows).
__global__ __launch_bounds__(256) void norm_linear(
    const float* __restrict__ adj, const float* __restrict__ rowsum,
    const uint* __restrict__ flags, float* __restrict__ out, int n, int onlyNeg)
{
    if (onlyNeg && flags[0] == 0u) return;
    const int i = blockIdx.y;
    const float di = rsqrtf(rowsum[i]);
    const int j0 = blockIdx.x * 4096 + threadIdx.x * 4;
    #pragma unroll
    for (int k = 0; k < 4; ++k) {
        const int j = j0 + k * 1024;
        if (j >= n) return;
        f32x4 a = __builtin_nontemporal_load((const f32x4*)(adj + (size_t)i * n + j));
        float4 rj = *(const float4*)(rowsum + j);
        ntst(out + (size_t)i * n + j,
             di * a.x * rsqrtf(rj.x), di * a.y * rsqrtf(rj.y),
             di * a.z * rsqrtf(rj.z), di * a.w * rsqrtf(rj.w));
    }
}

// ---------------------------------------------------------------------------
extern "C" void kernel_launch(void* const* d_in, const int* in_sizes, int n_in,
                              void* d_out, int out_size, void* d_ws, size_t ws_size,
                              hipStream_t stream)
{
    const float* F = (const float*)d_in[0];   // (n, d) fp32
    const float* A = (const float*)d_in[1];   // (d, 1) fp32
    const int d = in_sizes[1];                // 256
    const int n = in_sizes[0] / d;            // 8192

    float* nrm    = (float*)d_out;            // normalized, n*n
    float* adj    = nrm + (size_t)n * n;      // adjacency, n*n
    uint*  flags  = (uint*)d_ws;              // [0]=negflag [1]=min [2]=max
    float* rowsum = (float*)d_ws + 8;

    // Q: quantized features, n*d bytes (2 MB). Big-ws: Q in ws tail -> sad16
    // pipeline. Small-ws: Q in nrm region -> r7-proven flow.
    const size_t wsHead = (((size_t)(8 + n) * 4) + 255) & ~(size_t)255;
    const size_t need = wsHead + (size_t)n * d;
    const bool big = (ws_size >= need);
    uint* Q = big ? (uint*)((char*)d_ws + wsHead) : (uint*)d_out;

    init_kernel<<<dim3(1), dim3(256), 0, stream>>>(flags, A, d);
    minmax_kernel<<<dim3(256), dim3(256), 0, stream>>>(F, A, flags, n, d);
    quant_kernel<<<dim3(n / 32), dim3(256), 0, stream>>>(F, A, flags, Q, rowsum, n, d);

    const int nb = n / 128;
    const int tri = nb * (nb + 1) / 2;
    dim3 gridL((n + 4095) / 4096, n);

    if (big) {
        pass1_sad16<<<dim3(tri), dim3(256), 0, stream>>>(Q, flags, (ushort_t*)nrm,
                                                         rowsum, n, d);
        adj_fp32_kernel<<<dim3(1024), dim3(256), 0, stream>>>(F, A, flags, adj, rowsum, n, d);
        norm_tiled<<<dim3(tri), dim3(256), 0, stream>>>((const ushort_t*)nrm, flags,
                                                        rowsum, adj, nrm, n);
        norm_linear<<<gridL, dim3(256), 0, stream>>>(adj, rowsum, flags, nrm, n, 1);
    } else {
        pass1_sadW<<<dim3(tri), dim3(256), 0, stream>>>(Q, flags, adj, rowsum, n, d);
        adj_fp32_kernel<<<dim3(1024), dim3(256), 0, stream>>>(F, A, flags, adj, rowsum, n, d);
        norm_linear<<<gridL, dim3(256), 0, stream>>>(adj, rowsum, flags, nrm, n, 0);
    }
}

// Round 10
// 294.578 us; speedup vs baseline: 1.0775x; 1.0775x over previous
//
#include <hip/hip_runtime.h>
#include <math.h>

typedef unsigned int uint;
typedef float f32x4 __attribute__((ext_vector_type(4)));

// monotonic float<->uint encoding for atomic min/max
__device__ __forceinline__ uint fenc(float f) {
    uint u = __float_as_uint(f);
    return (u & 0x80000000u) ? ~u : (u | 0x80000000u);
}
__device__ __forceinline__ float fdec(uint u) {
    uint v = (u & 0x80000000u) ? (u & 0x7FFFFFFFu) : ~u;
    return __uint_as_float(v);
}

// NT store: destinations never re-read (nrm, adj-lower mirror)
__device__ __forceinline__ void ntst(float* p, float a, float b, float c, float d) {
    f32x4 t; t.x = a; t.y = b; t.z = c; t.w = d;
    __builtin_nontemporal_store(t, (f32x4*)p);
}
// cacheable store: adj-upper (re-read by pass2; 134 MB < 256 MB L3)
__device__ __forceinline__ void cst(float* p, float a, float b, float c, float d) {
    f32x4 t; t.x = a; t.y = b; t.z = c; t.w = d;
    *(f32x4*)p = t;
}

// ---------------------------------------------------------------------------
// init (1 block): flags + negative-weight scan
__global__ __launch_bounds__(256) void init_kernel(uint* __restrict__ flags,
                                                   const float* __restrict__ A,
                                                   int d)
{
    const int t = threadIdx.x;
    if (t == 0) { flags[0] = 0u; flags[1] = 0xFFFFFFFFu; flags[2] = 0u; }
    __syncthreads();
    for (int k = t; k < d; k += 256)
        if (A[k] < 0.f) atomicOr(&flags[0], 1u);
}

// ---------------------------------------------------------------------------
// global min/max of G = |a_d| * F[i][d]
__global__ __launch_bounds__(256) void minmax_kernel(const float* __restrict__ F,
                                                     const float* __restrict__ A,
                                                     uint* __restrict__ flags,
                                                     int n, int d)
{
    const int total4 = n * d / 4;
    float lmin = 3.4e38f, lmax = -3.4e38f;
    for (int e4 = blockIdx.x * 256 + threadIdx.x; e4 < total4; e4 += gridDim.x * 256) {
        int e = e4 * 4;
        int dk = e % d;
        float4 f = *(const float4*)(F + e);
        float4 a = *(const float4*)(A + dk);
        float g0 = fabsf(a.x) * f.x, g1 = fabsf(a.y) * f.y;
        float g2 = fabsf(a.z) * f.z, g3 = fabsf(a.w) * f.w;
        lmin = fminf(lmin, fminf(fminf(g0, g1), fminf(g2, g3)));
        lmax = fmaxf(lmax, fmaxf(fmaxf(g0, g1), fmaxf(g2, g3)));
    }
    #pragma unroll
    for (int m = 1; m < 64; m <<= 1) {
        lmin = fminf(lmin, __shfl_xor(lmin, m));
        lmax = fmaxf(lmax, __shfl_xor(lmax, m));
    }
    if ((threadIdx.x & 63) == 0) {
        atomicMin(&flags[1], fenc(lmin));
        atomicMax(&flags[2], fenc(lmax));
    }
}

// ---------------------------------------------------------------------------
// quantize G = a_d*F (a_d>0 dims; others -> 0) to u8, k-major u32 [d/4][n];
// also zeroes rowsum (block b owns rows b*32..b*32+31).
__global__ __launch_bounds__(256) void quant_kernel(const float* __restrict__ F,
                                                    const float* __restrict__ A,
                                                    const uint* __restrict__ flags,
                                                    uint* __restrict__ Q,
                                                    float* __restrict__ rowsum,
                                                    int n, int d)
{
    const int t = threadIdx.x;
    const int r = blockIdx.x * 32 + (t & 31);
    if (t < 32) rowsum[blockIdx.x * 32 + t] = 0.f;
    const int kqb = t >> 5;
    const int d4 = d >> 2;
    const float gmin = fdec(flags[1]), gmax = fdec(flags[2]);
    const float span = gmax - gmin;
    const float inv = span > 0.f ? 255.f / span : 0.f;
    for (int kq = kqb; kq < d4; kq += 8) {
        float4 f = *(const float4*)(F + (size_t)r * d + kq * 4);
        float4 a = *(const float4*)(A + kq * 4);
        uint q0 = 0, q1 = 0, q2 = 0, q3 = 0;
        if (a.x > 0.f) q0 = (uint)fminf(fmaxf((a.x * f.x - gmin) * inv + 0.5f, 0.f), 255.f);
        if (a.y > 0.f) q1 = (uint)fminf(fmaxf((a.y * f.y - gmin) * inv + 0.5f, 0.f), 255.f);
        if (a.z > 0.f) q2 = (uint)fminf(fmaxf((a.z * f.z - gmin) * inv + 0.5f, 0.f), 255.f);
        if (a.w > 0.f) q3 = (uint)fminf(fmaxf((a.w * f.w - gmin) * inv + 0.5f, 0.f), 255.f);
        Q[(size_t)kq * n + r] = q0 | (q1 << 8) | (q2 << 16) | (q3 << 24);
    }
}

// ---------------------------------------------------------------------------
// shared SAD tile core (r5/r7-proven pipeline)
__device__ __forceinline__ void sad_core(const uint* __restrict__ Q, int n, int chunks,
                                         int i0, int j0, int t,
                                         uint (&acc)[8][8],
                                         uint (&As)[16][128], uint (&Bs)[16][128])
{
    const int tx = t & 15, ty = t >> 4;
    const int kk0 = t >> 5;
    const int col = 4 * (t & 31);

    uint4 sa[2], sb[2];
    #pragma unroll
    for (int j = 0; j < 2; ++j) {
        size_t g = ((size_t)(kk0 + 8 * j)) * n;
        sa[j] = *(const uint4*)(Q + g + i0 + col);
        sb[j] = *(const uint4*)(Q + g + j0 + col);
    }

    for (int c = 0; c < chunks; ++c) {
        ((uint4*)&As[0][0])[t]       = sa[0];
        ((uint4*)&As[0][0])[256 + t] = sa[1];
        ((uint4*)&Bs[0][0])[t]       = sb[0];
        ((uint4*)&Bs[0][0])[256 + t] = sb[1];
        __syncthreads();

        if (c + 1 < chunks) {
            #pragma unroll
            for (int j = 0; j < 2; ++j) {
                size_t g = ((size_t)((c + 1) * 16 + kk0 + 8 * j)) * n;
                sa[j] = *(const uint4*)(Q + g + i0 + col);
                sb[j] = *(const uint4*)(Q + g + j0 + col);
            }
        }

        #pragma unroll
        for (int kk = 0; kk < 16; ++kk) {
            uint ar[8], br[8];
            *(uint4*)&ar[0] = *(const uint4*)&As[kk][4 * ty];
            *(uint4*)&ar[4] = *(const uint4*)&As[kk][64 + 4 * ty];
            *(uint4*)&br[0] = *(const uint4*)&Bs[kk][4 * tx];
            *(uint4*)&br[4] = *(const uint4*)&Bs[kk][64 + 4 * tx];
            #pragma unroll
            for (int m = 0; m < 8; ++m)
                #pragma unroll
                for (int cc = 0; cc < 8; ++cc)
                    acc[m][cc] = __builtin_amdgcn_sad_u8(ar[m], br[cc], acc[m][cc]);
        }
        __syncthreads();
    }
}

// triangular block decode: b -> (bx >= by)
__device__ __forceinline__ void tri_decode(int b, int& bx, int& by) {
    bx = (int)((sqrtf(8.f * (float)b + 1.f) - 1.f) * 0.5f);
    while ((bx + 1) * (bx + 2) / 2 <= b) ++bx;
    while (bx * (bx + 1) / 2 > b) --bx;
    by = b - bx * (bx + 1) / 2;
}

// ---------------------------------------------------------------------------
// Pass 1 (fast path): two tiles per block. Per tile: SAD -> exp -> store
// UPPER-DIRECT adjacency only (coalesced, cacheable -> L3 for pass2's read)
// + rowsum atomics (row and col sums). Mirror stores live in pass2.
__global__ __launch_bounds__(256, 3) void pass1_sad(const uint* __restrict__ Q,
                                                    const uint* __restrict__ flags,
                                                    float* __restrict__ adj,
                                                    float* __restrict__ rowsum,
                                                    int n, int d)
{
    if (flags[0] != 0u) return;

    __shared__ uint As[16][128];
    __shared__ uint Bs[16][128];

    const int t = threadIdx.x, tx = t & 15, ty = t >> 4;
    const float gmin = fdec(flags[1]), gmax = fdec(flags[2]);
    const float nstep = (gmin - gmax) * (1.f / 255.f);   // -step

    #pragma unroll 1
    for (int tt = 0; tt < 2; ++tt) {
        const int b = blockIdx.x * 2 + tt;
        int bx, by; tri_decode(b, bx, by);
        const int i0 = by * 128, j0 = bx * 128;
        const bool diag = (bx == by);

        uint acc[8][8] = {};
        sad_core(Q, n, (d >> 2) >> 4, i0, j0, t, acc, As, Bs);

        // convert in place: acc[m][cc] := f32 bits of e = exp(-step*sad)
        #pragma unroll
        for (int m = 0; m < 8; ++m)
            #pragma unroll
            for (int cc = 0; cc < 8; ++cc)
                acc[m][cc] = __float_as_uint(__expf(nstep * (float)acc[m][cc]));

        // upper-direct stores (rows i0..): 256 B contiguous per 16-lane group
        #pragma unroll
        for (int m = 0; m < 8; ++m) {
            const int row = i0 + (m >> 2) * 64 + 4 * ty + (m & 3);
            #pragma unroll
            for (int qh = 0; qh < 2; ++qh)
                cst(adj + (size_t)row * n + j0 + qh * 64 + 4 * tx,
                    __uint_as_float(acc[m][qh * 4 + 0]),
                    __uint_as_float(acc[m][qh * 4 + 1]),
                    __uint_as_float(acc[m][qh * 4 + 2]),
                    __uint_as_float(acc[m][qh * 4 + 3]));
        }

        // reductions + atomics
        #pragma unroll
        for (int m = 0; m < 8; ++m) {
            const int row = i0 + (m >> 2) * 64 + 4 * ty + (m & 3);
            float rs = 0.f;
            #pragma unroll
            for (int cc = 0; cc < 8; ++cc) rs += __uint_as_float(acc[m][cc]);
            rs += __shfl_xor(rs, 1);
            rs += __shfl_xor(rs, 2);
            rs += __shfl_xor(rs, 4);
            rs += __shfl_xor(rs, 8);
            if (tx == 0) atomicAdd(rowsum + row, rs);
        }
        if (!diag) {
            float cs[8];
            #pragma unroll
            for (int cc = 0; cc < 8; ++cc) {
                float s = 0.f;
                #pragma unroll
                for (int m = 0; m < 8; ++m) s += __uint_as_float(acc[m][cc]);
                s += __shfl_xor(s, 16);
                s += __shfl_xor(s, 32);
                cs[cc] = s;
            }
            if ((t & 48) == 0) {
                #pragma unroll
                for (int qh = 0; qh < 2; ++qh)
                    #pragma unroll
                    for (int cc = 0; cc < 4; ++cc)
                        atomicAdd(rowsum + j0 + qh * 64 + 4 * tx + cc, cs[qh * 4 + cc]);
            }
        }
        // LDS safe to restage: sad_core ended with __syncthreads, and the
        // epilogue touches no LDS.
    }
}

// ---------------------------------------------------------------------------
// Pass 2 (fast path): pure streaming tile kernel. Per upper tile: read own
// e-tile from adj (L3-favored), write adj-lower mirror + nrm-upper + nrm-lower
// with rsqrt(rowsum) folded. No LDS, no barriers, no aliasing.
__global__ __launch_bounds__(256) void pass2_norm(const float* __restrict__ adj_r,
                                                  float* __restrict__ adj,
                                                  const float* __restrict__ rowsum,
                                                  const uint* __restrict__ flags,
                                                  float* __restrict__ nrm, int n)
{
    if (flags[0] != 0u) return;

    int bx, by; tri_decode(blockIdx.x, bx, by);
    const int t = threadIdx.x, tx = t & 15, ty = t >> 4;
    const int i0 = by * 128, j0 = bx * 128;
    const bool diag = (bx == by);

    float e[8][8];
    #pragma unroll
    for (int m = 0; m < 8; ++m) {
        const int row = i0 + (m >> 2) * 64 + 4 * ty + (m & 3);
        #pragma unroll
        for (int qh = 0; qh < 2; ++qh) {
            float4 v = *(const float4*)(adj_r + (size_t)row * n + j0 + qh * 64 + 4 * tx);
            e[m][qh * 4 + 0] = v.x; e[m][qh * 4 + 1] = v.y;
            e[m][qh * 4 + 2] = v.z; e[m][qh * 4 + 3] = v.w;
        }
    }

    float dr[8], dc[8];
    #pragma unroll
    for (int m = 0; m < 8; ++m)
        dr[m] = rsqrtf(rowsum[i0 + (m >> 2) * 64 + 4 * ty + (m & 3)]);
    {
        float4 c0 = *(const float4*)(rowsum + j0 + 4 * tx);
        float4 c1 = *(const float4*)(rowsum + j0 + 64 + 4 * tx);
        dc[0] = rsqrtf(c0.x); dc[1] = rsqrtf(c0.y);
        dc[2] = rsqrtf(c0.z); dc[3] = rsqrtf(c0.w);
        dc[4] = rsqrtf(c1.x); dc[5] = rsqrtf(c1.y);
        dc[6] = rsqrtf(c1.z); dc[7] = rsqrtf(c1.w);
    }

    // nrm upper direct
    #pragma unroll
    for (int m = 0; m < 8; ++m) {
        const int row = i0 + (m >> 2) * 64 + 4 * ty + (m & 3);
        const float dm = dr[m];
        #pragma unroll
        for (int qh = 0; qh < 2; ++qh)
            ntst(nrm + (size_t)row * n + j0 + qh * 64 + 4 * tx,
                 e[m][qh * 4 + 0] * dm * dc[qh * 4 + 0],
                 e[m][qh * 4 + 1] * dm * dc[qh * 4 + 1],
                 e[m][qh * 4 + 2] * dm * dc[qh * 4 + 2],
                 e[m][qh * 4 + 3] * dm * dc[qh * 4 + 3]);
    }

    // lower mirrors (adj + nrm), off-diagonal only
    if (!diag) {
        #pragma unroll
        for (int h = 0; h < 2; ++h)
            #pragma unroll
            for (int qh = 0; qh < 2; ++qh)
                #pragma unroll
                for (int cc = 0; cc < 4; ++cc) {
                    const int r = j0 + qh * 64 + 4 * tx + cc;
                    const float dcv = dc[qh * 4 + cc];
                    float* ap = adj + (size_t)r * n + i0 + 64 * h + 4 * ty;
                    float* np = nrm + (size_t)r * n + i0 + 64 * h + 4 * ty;
                    ntst(ap, e[4 * h + 0][qh * 4 + cc], e[4 * h + 1][qh * 4 + cc],
                             e[4 * h + 2][qh * 4 + cc], e[4 * h + 3][qh * 4 + cc]);
                    ntst(np, e[4 * h + 0][qh * 4 + cc] * dr[4 * h + 0] * dcv,
                             e[4 * h + 1][qh * 4 + cc] * dr[4 * h + 1] * dcv,
                             e[4 * h + 2][qh * 4 + cc] * dr[4 * h + 2] * dcv,
                             e[4 * h + 3][qh * 4 + cc] * dr[4 * h + 3] * dcv);
                }
    }
}

// ---------------------------------------------------------------------------
// Slow fp32 fallback (negflag!=0): persistent grid over all square tiles.
__global__ __launch_bounds__(256) void adj_fp32_kernel(
    const float* __restrict__ F, const float* __restrict__ A,
    const uint* __restrict__ flags,
    float* __restrict__ adj, float* __restrict__ rowsum, int n, int d)
{
    if (flags[0] == 0u) return;

    __shared__ __align__(16) float As[32][132];
    __shared__ __align__(16) float Bs[32][132];
    __shared__ float aw[256];

    const int t  = threadIdx.x;
    const int tx = t & 15;
    const int ty = t >> 4;
    const int nb = n / 128;

    for (int k = t; k < d; k += 256) aw[k] = A[k];

    for (int bt = blockIdx.x; bt < nb * nb; bt += gridDim.x) {
        const int i0 = (bt / nb) * 128;
        const int j0 = (bt % nb) * 128;

        float acc[2][2][4][4] = {};
        const int lr = t >> 3;
        const int lk = (t & 7) << 2;

        for (int kc = 0; kc < d; kc += 32) {
            __syncthreads();
            #pragma unroll
            for (int s = 0; s < 4; ++s) {
                int r = lr + 32 * s;
                float4 v = *(const float4*)(F + (size_t)(i0 + r) * d + kc + lk);
                As[lk + 0][r] = v.x; As[lk + 1][r] = v.y;
                As[lk + 2][r] = v.z; As[lk + 3][r] = v.w;
                float4 u = *(const float4*)(F + (size_t)(j0 + r) * d + kc + lk);
                Bs[lk + 0][r] = u.x; Bs[lk + 1][r] = u.y;
                Bs[lk + 2][r] = u.z; Bs[lk + 3][r] = u.w;
            }
            __syncthreads();

            #pragma unroll
            for (int k = 0; k < 32; ++k) {
                float av[2][4], bv[2][4];
                *(float4*)&av[0][0] = *(const float4*)&As[k][4 * ty];
                *(float4*)&av[1][0] = *(const float4*)&As[k][64 + 4 * ty];
                *(float4*)&bv[0][0] = *(const float4*)&Bs[k][4 * tx];
                *(float4*)&bv[1][0] = *(const float4*)&Bs[k][64 + 4 * tx];
                const float w = aw[kc + k];
                #pragma unroll
                for (int p = 0; p < 2; ++p)
                    #pragma unroll
                    for (int m = 0; m < 4; ++m)
                        #pragma unroll
                        for (int q = 0; q < 2; ++q)
                            #pragma unroll
                            for (int c = 0; c < 4; ++c)
                                acc[p][q][m][c] += fabsf(av[p][m] - bv[q][c]) * w;
            }
        }

        #pragma unroll
        for (int p = 0; p < 2; ++p) {
            #pragma unroll
            for (int m = 0; m < 4; ++m) {
                const int row = i0 + p * 64 + ty * 4 + m;
                float rs = 0.f;
                #pragma unroll
                for (int q = 0; q < 2; ++q) {
                    float4 v;
                    v.x = __expf(-fmaxf(acc[p][q][m][0], 0.f));
                    v.y = __expf(-fmaxf(acc[p][q][m][1], 0.f));
                    v.z = __expf(-fmaxf(acc[p][q][m][2], 0.f));
                    v.w = __expf(-fmaxf(acc[p][q][m][3], 0.f));
                    rs += (v.x + v.y) + (v.z + v.w);
                    *(float4*)(adj + (size_t)row * n + j0 + q * 64 + tx * 4) = v;
                }
                rs += __shfl_xor(rs, 1);
                rs += __shfl_xor(rs, 2);
                rs += __shfl_xor(rs, 4);
                rs += __shfl_xor(rs, 8);
                if (tx == 0) atomicAdd(rowsum + row, rs);
            }
        }
        __syncthreads();
    }
}

// ---------------------------------------------------------------------------
// linear norm with rsqrt folded — fallback (negflag) path only.
__global__ __launch_bounds__(256) void norm_linear(
    const float* __restrict__ adj, const float* __restrict__ rowsum,
    const uint* __restrict__ flags, float* __restrict__ out, int n)
{
    if (flags[0] == 0u) return;
    const int i = blockIdx.y;
    const float di = rsqrtf(rowsum[i]);
    const int j0 = blockIdx.x * 4096 + threadIdx.x * 4;
    #pragma unroll
    for (int k = 0; k < 4; ++k) {
        const int j = j0 + k * 1024;
        if (j >= n) return;
        f32x4 a = __builtin_nontemporal_load((const f32x4*)(adj + (size_t)i * n + j));
        float4 rj = *(const float4*)(rowsum + j);
        ntst(out + (size_t)i * n + j,
             di * a.x * rsqrtf(rj.x), di * a.y * rsqrtf(rj.y),
             di * a.z * rsqrtf(rj.z), di * a.w * rsqrtf(rj.w));
    }
}

// ---------------------------------------------------------------------------
extern "C" void kernel_launch(void* const* d_in, const int* in_sizes, int n_in,
                              void* d_out, int out_size, void* d_ws, size_t ws_size,
                              hipStream_t stream)
{
    const float* F = (const float*)d_in[0];   // (n, d) fp32
    const float* A = (const float*)d_in[1];   // (d, 1) fp32
    const int d = in_sizes[1];                // 256
    const int n = in_sizes[0] / d;            // 8192

    float* nrm    = (float*)d_out;            // normalized, n*n
    float* adj    = nrm + (size_t)n * n;      // adjacency, n*n
    uint*  flags  = (uint*)d_ws;              // [0]=negflag [1]=min [2]=max
    float* rowsum = (float*)d_ws + 8;
    // Q: quantized features (2 MB) in the nrm region; consumed by pass1
    // (which fully precedes pass2's nrm writes in stream order).
    uint* Q = (uint*)d_out;

    init_kernel<<<dim3(1), dim3(256), 0, stream>>>(flags, A, d);
    minmax_kernel<<<dim3(256), dim3(256), 0, stream>>>(F, A, flags, n, d);
    quant_kernel<<<dim3(n / 32), dim3(256), 0, stream>>>(F, A, flags, Q, rowsum, n, d);

    const int nb = n / 128;                   // 64
    const int tri = nb * (nb + 1) / 2;        // 2080
    pass1_sad<<<dim3(tri / 2), dim3(256), 0, stream>>>(Q, flags, adj, rowsum, n, d);
    adj_fp32_kernel<<<dim3(1024), dim3(256), 0, stream>>>(F, A, flags, adj, rowsum, n, d);

    pass2_norm<<<dim3(tri), dim3(256), 0, stream>>>(adj, adj, rowsum, flags, nrm, n);
    dim3 gridL((n + 4095) / 4096, n);
    norm_linear<<<gridL, dim3(256), 0, stream>>>(adj, rowsum, flags, nrm, n);
}